// Round 4
// baseline (11356.281 us; speedup 1.0000x reference)
//
#include <hip/hip_runtime.h>
#include <math.h>

static constexpr int B_ = 512;
static constexpr int T_ = 16;
static constexpr int S_ = 64;
static constexpr int K_ = 32;
static constexpr int N_ = 1024;   // T_*S_

// ---------------- init: rowmap identity + logdet zero ----------------
__global__ void initk(int* __restrict__ rowmap, float* __restrict__ logdet) {
  int idx = blockIdx.x * 256 + threadIdx.x;
  if (idx < K_ * N_) rowmap[idx] = idx & (N_ - 1);
  if (idx < K_) logdet[idx] = 0.f;
}

// ---------------- build block-Toeplitz M[k][row][col], LDS-transpose version ----
// block (i=by rows, j=bx cols): M_block = A[i-j]^T if i>=j else A[j-i]
__global__ __launch_bounds__(256) void buildM(const float* __restrict__ A, float* __restrict__ M) {
  int k = blockIdx.z, i = blockIdx.y, j = blockIdx.x;
  int d = i - j;
  int ad = d >= 0 ? d : -d;
  const float* Ad = A + ((size_t)(ad * K_ + k) << 12);
  float* out = M + ((size_t)k << 20) + (size_t)(i * 64) * N_ + j * 64;
  int tid = threadIdx.x;
  if (d < 0) {
    // direct copy out[a][b] = Ad[a][b]
    for (int x = tid; x < 1024; x += 256) {
      int a = x >> 4, b4 = (x & 15) << 2;
      *(float4*)(out + (size_t)a * N_ + b4) = *(const float4*)(Ad + a * 64 + b4);
    }
  } else {
    // transpose via LDS: out[a][b] = Ad[b][a]
    __shared__ float ts[64][65];
    for (int x = tid; x < 1024; x += 256) {
      int r = x >> 4, c4 = (x & 15) << 2;
      float4 v = *(const float4*)(Ad + r * 64 + c4);
      ts[c4 + 0][r] = v.x; ts[c4 + 1][r] = v.y; ts[c4 + 2][r] = v.z; ts[c4 + 3][r] = v.w;
    }
    __syncthreads();
    for (int x = tid; x < 1024; x += 256) {
      int a = x >> 4, b4 = (x & 15) << 2;
      float4 v;
      v.x = ts[a][b4 + 0]; v.y = ts[a][b4 + 1]; v.z = ts[a][b4 + 2]; v.w = ts[a][b4 + 3];
      *(float4*)(out + (size_t)a * N_ + b4) = v;
    }
  }
}

// ---------------- prep: r[k][j][s] and cterm[k] ----------------
__global__ __launch_bounds__(256) void prepk(const float* __restrict__ A, const float* __restrict__ mu,
                                             float* __restrict__ rbuf, float* __restrict__ cterm) {
  int k = blockIdx.x;
  __shared__ float smu[64];
  __shared__ float sp[1024], sq[1024];
  int tid = threadIdx.x;
  if (tid < 64) smu[tid] = mu[k * 64 + tid];
  __syncthreads();
  for (int idx = tid; idx < 1024; idx += 256) {
    int d = idx >> 6, s = idx & 63;
    const float* Ad = A + ((size_t)(d * K_ + k) << 12);
    float ap = 0.f, aq = 0.f;
    for (int s2 = 0; s2 < 64; ++s2) {
      ap += Ad[s * 64 + s2] * smu[s2];
      aq += Ad[s2 * 64 + s] * smu[s2];
    }
    sp[idx] = ap; sq[idx] = aq;
  }
  __syncthreads();
  for (int idx = tid; idx < 1024; idx += 256) {
    int j = idx >> 6, s = idx & 63;
    float acc = 0.5f * (sp[s] + sq[s]);
    for (int d = 1; d < 16; ++d) {
      if (d <= 15 - j) acc += sp[d * 64 + s];
      if (d <= j)      acc += sq[d * 64 + s];
    }
    rbuf[k * 1024 + idx] = acc;
  }
  if (tid < 64) {
    float a = 16.f * sp[tid];
    for (int d = 1; d < 16; ++d) a += 2.f * (float)(16 - d) * sp[d * 64 + tid];
    a *= smu[tid];
    for (int off = 32; off; off >>= 1) a += __shfl_xor(a, off);
    if (tid == 0) cterm[k] = a;
  }
}

// ---------------- Q kernel: Qp[g][b][k] partial quadratic forms ----------------
__global__ __launch_bounds__(256) void qkern(const float* __restrict__ X, const float* __restrict__ A,
                                             float* __restrict__ Qp) {
  int g = blockIdx.x;        // d in {g, g+4, g+8, g+12}
  int btile = blockIdx.y;    // 4 batches each
  __shared__ float Xs[4][1024];
  __shared__ float Cs[4][4096];
  int tid = threadIdx.x;
  int wave = tid >> 6, lane = tid & 63;
  for (int t = tid; t < 4096; t += 256) {
    int bb = t >> 10, e = t & 1023;
    Xs[bb][e] = X[(size_t)(btile * 4 + bb) * 1024 + e];
  }
  float regQ[4][8];
#pragma unroll
  for (int bb = 0; bb < 4; ++bb)
#pragma unroll
    for (int kk = 0; kk < 8; ++kk) regQ[bb][kk] = 0.f;

  int a0 = (tid >> 4) << 2;
  int v0 = (tid & 15) << 2;
  for (int dd = 0; dd < 4; ++dd) {
    int d = g + (dd << 2);
    __syncthreads();
    for (int bb = 0; bb < 4; ++bb) {
      float4 r0 = {0,0,0,0}, r1 = {0,0,0,0}, r2 = {0,0,0,0}, r3 = {0,0,0,0};
      for (int j = 0; j + d < 16; ++j) {
        const float4 xa = *(const float4*)&Xs[bb][j * 64 + a0];
        const float4 xv = *(const float4*)&Xs[bb][(j + d) * 64 + v0];
        r0.x += xa.x * xv.x; r0.y += xa.x * xv.y; r0.z += xa.x * xv.z; r0.w += xa.x * xv.w;
        r1.x += xa.y * xv.x; r1.y += xa.y * xv.y; r1.z += xa.y * xv.z; r1.w += xa.y * xv.w;
        r2.x += xa.z * xv.x; r2.y += xa.z * xv.y; r2.z += xa.z * xv.z; r2.w += xa.z * xv.w;
        r3.x += xa.w * xv.x; r3.y += xa.w * xv.y; r3.z += xa.w * xv.z; r3.w += xa.w * xv.w;
      }
      *(float4*)&Cs[bb][(a0 + 0) * 64 + v0] = r0;
      *(float4*)&Cs[bb][(a0 + 1) * 64 + v0] = r1;
      *(float4*)&Cs[bb][(a0 + 2) * 64 + v0] = r2;
      *(float4*)&Cs[bb][(a0 + 3) * 64 + v0] = r3;
    }
    __syncthreads();
    float w = (d == 0) ? 1.f : 2.f;
    for (int ch = 0; ch < 16; ++ch) {
      int e4 = (ch * 64 + lane) << 2;
      float4 cv[4];
#pragma unroll
      for (int bb = 0; bb < 4; ++bb) {
        float4 t4 = *(const float4*)&Cs[bb][e4];
        cv[bb].x = w * t4.x; cv[bb].y = w * t4.y; cv[bb].z = w * t4.z; cv[bb].w = w * t4.w;
      }
#pragma unroll
      for (int kk = 0; kk < 8; ++kk) {
        int k = wave + (kk << 2);
        const float4 av = *(const float4*)(A + (((size_t)(d * K_ + k)) << 12) + e4);
#pragma unroll
        for (int bb = 0; bb < 4; ++bb)
          regQ[bb][kk] += av.x * cv[bb].x + av.y * cv[bb].y + av.z * cv[bb].z + av.w * cv[bb].w;
      }
    }
  }
#pragma unroll
  for (int bb = 0; bb < 4; ++bb)
#pragma unroll
    for (int kk = 0; kk < 8; ++kk) {
      float v = regQ[bb][kk];
      for (int off = 32; off; off >>= 1) v += __shfl_xor(v, off);
      regQ[bb][kk] = v;
    }
  if (lane == 0) {
    int b = btile * 4;
#pragma unroll
    for (int bb = 0; bb < 4; ++bb)
#pragma unroll
      for (int kk = 0; kk < 8; ++kk)
        Qp[((size_t)(g * B_ + b + bb) << 5) + (wave + (kk << 2))] = regQ[bb][kk];
  }
}

// ---------------- LU panel (nb=64) v4: thread-per-row registers, 2 barriers/step ----
__global__ __launch_bounds__(1024) void panelk(float* __restrict__ M, int* __restrict__ rowmap,
                                               float* __restrict__ logdet, int j0) {
  int k = blockIdx.x;
  float* Mk = M + ((size_t)k << 20);
  int* rmk = rowmap + (k << 10);
  int m = N_ - j0;
  int t = threadIdx.x;
  int lane = t & 63, wid = t >> 6;
  int nw = blockDim.x >> 6;

  __shared__ float bufP[64];
  __shared__ float bufJ[64];
  __shared__ int origP, origJ;
  __shared__ float candv[16];
  __shared__ int candi[16];

  float r[64];
  int myorig = -1;
  float mydiag = 1.f;
  bool act = (t < m);
  if (act) {
    myorig = rmk[j0 + t];
    const float* src = Mk + (size_t)myorig * N_ + j0;
#pragma unroll
    for (int c4 = 0; c4 < 16; ++c4) *(float4*)&r[c4 * 4] = *(const float4*)(src + c4 * 4);
  }

  int pcur;
  // ---- prime: select pivot for column 0, stage it ----
  {
    float bv = act ? fabsf(r[0]) : -1.f;
    int bi = t;
#pragma unroll
    for (int off = 32; off; off >>= 1) {
      float ov = __shfl_xor(bv, off);
      int oi = __shfl_xor(bi, off);
      if (ov > bv) { bv = ov; bi = oi; }
    }
    if (lane == 0) { candv[wid] = bv; candi[wid] = bi; }
    __syncthreads();
    float cv = -1.f; int ci = 0;
    for (int w = 0; w < nw; ++w) { float v = candv[w]; if (v > cv) { cv = v; ci = candi[w]; } }
    pcur = ci;
    if (t == pcur) {
#pragma unroll
      for (int c4 = 0; c4 < 16; ++c4) *(float4*)&bufP[c4 * 4] = *(const float4*)&r[c4 * 4];
      origP = myorig;
    }
    if (pcur != 0 && t == 0) {
#pragma unroll
      for (int c4 = 0; c4 < 16; ++c4) *(float4*)&bufJ[c4 * 4] = *(const float4*)&r[c4 * 4];
      origJ = myorig;
    }
    __syncthreads();
  }

#pragma unroll
  for (int jj = 0; jj < 64; ++jj) {
    // ---- adopt swap ----
    if (pcur != jj) {
      if (t == jj) {
#pragma unroll
        for (int c4 = 0; c4 < 16; ++c4) *(float4*)&r[c4 * 4] = *(const float4*)&bufP[c4 * 4];
        myorig = origP;
      } else if (t == pcur) {
#pragma unroll
        for (int c4 = 0; c4 < 16; ++c4) *(float4*)&r[c4 * 4] = *(const float4*)&bufJ[c4 * 4];
        myorig = origJ;
      }
    }
    // ---- broadcast pivot row chunks (only needed columns survive DCE) ----
    float pr[64];
#pragma unroll
    for (int c4 = jj >> 2; c4 < 16; ++c4) *(float4*)&pr[c4 * 4] = *(const float4*)&bufP[c4 * 4];
    float pv = pr[jj];
    if (t == jj) mydiag = pv;
    // ---- rank-1 update + candidate for next column ----
    float cand = -1.f;
    if (act && t > jj) {
      float mult = r[jj] / pv;
      r[jj] = mult;
#pragma unroll
      for (int c = jj + 1; c < 64; ++c) r[c] -= mult * pr[c];
      if (jj < 63) cand = fabsf(r[jj + 1]);
    }
    if (jj < 63) {
      float bv = cand; int bi = t;
#pragma unroll
      for (int off = 32; off; off >>= 1) {
        float ov = __shfl_xor(bv, off);
        int oi = __shfl_xor(bi, off);
        if (ov > bv) { bv = ov; bi = oi; }
      }
      if (lane == 0) { candv[wid] = bv; candi[wid] = bi; }
      __syncthreads();
      float cv = -1.f; int ci = jj + 1;
      for (int w = 0; w < nw; ++w) { float v = candv[w]; if (v > cv) { cv = v; ci = candi[w]; } }
      int pn = ci;
      if (t == pn) {
#pragma unroll
        for (int c4 = 0; c4 < 16; ++c4) *(float4*)&bufP[c4 * 4] = *(const float4*)&r[c4 * 4];
        origP = myorig;
      }
      if (pn != jj + 1 && t == jj + 1) {
#pragma unroll
        for (int c4 = 0; c4 < 16; ++c4) *(float4*)&bufJ[c4 * 4] = *(const float4*)&r[c4 * 4];
        origJ = myorig;
      }
      pcur = pn;
      __syncthreads();
    }
  }

  // ---- logdet from diagonals (threads 0..63 = wave 0) ----
  if (t < 64) {
    float lv = logf(fabsf(mydiag));
#pragma unroll
    for (int off = 32; off; off >>= 1) lv += __shfl_down(lv, off);
    if (t == 0) logdet[k] += lv;
  }
  // ---- export L/U panel (pivoted order, dense) + rowmap ----
  if (act) {
    float* dst = Mk + (size_t)(j0 + t) * N_ + j0;
#pragma unroll
    for (int c4 = 0; c4 < 16; ++c4) *(float4*)(dst + c4 * 4) = *(const float4*)&r[c4 * 4];
    rmk[j0 + t] = myorig;
  }
}

// ---------------- fused TRSM(K=64, 2 chunks) + GEMM update, 128x128 C tile ----------------
__global__ __launch_bounds__(256) void updatek(float* __restrict__ M, const int* __restrict__ rowmap, int j0) {
  int k = blockIdx.z;
  int mprime = N_ - j0 - 64;
  int r0 = blockIdx.y << 7;
  int c0 = blockIdx.x << 7;
  float* Mk = M + ((size_t)k << 20);
  const int* rmk = rowmap + (k << 10);
  __shared__ float l11[64 * 68];
  __shared__ float LtT[32 * 132];
  __shared__ float Ut[32 * 132];
  __shared__ int rowL[128];
  __shared__ int prU[64];
  int tid = threadIdx.x;

  if (tid < 128) rowL[tid] = (r0 + tid < mprime) ? rmk[j0 + 64 + r0 + tid] : -1;
  else if (tid < 192) prU[tid - 128] = rmk[j0 + (tid - 128)];
  // L11\U11 block: dense exported rows j0..j0+64, cols j0..j0+64
  for (int x = tid; x < 1024; x += 256) {
    int rr = x >> 4, q = (x & 15) << 2;
    *(float4*)&l11[rr * 68 + q] = *(const float4*)(Mk + (size_t)(j0 + rr) * N_ + j0 + q);
  }
  // LtT chunk A: L21 cols 0..31 (dense exported rows), transposed
  for (int x = tid; x < 1024; x += 256) {
    int rI = x >> 3, q = (x & 7) << 2;
    float4 v = {0.f, 0.f, 0.f, 0.f};
    if (r0 + rI < mprime) v = *(const float4*)(Mk + (size_t)(j0 + 64 + r0 + rI) * N_ + j0 + q);
    LtT[(q + 0) * 132 + rI] = v.x;
    LtT[(q + 1) * 132 + rI] = v.y;
    LtT[(q + 2) * 132 + rI] = v.z;
    LtT[(q + 3) * 132 + rI] = v.w;
  }
  __syncthreads();

  // TRSM chunk A: threads 0..127 own one column; u[0..31] stays in regs
  float u[32];
  bool tcol = tid < 128;
  int c = c0 + tid;
  bool ok = tcol && (c < mprime);
  if (tcol) {
#pragma unroll
    for (int rr = 0; rr < 32; ++rr) {
      float av = ok ? Mk[(size_t)prU[rr] * N_ + j0 + 64 + c] : 0.f;
#pragma unroll
      for (int tt = 0; tt < rr; ++tt) av -= l11[rr * 68 + tt] * u[tt];
      u[rr] = av;
      Ut[rr * 132 + tid] = av;
    }
  }
  __syncthreads();

  int tx = tid & 15, ty = tid >> 4;
  float4 acc[2][2][4];
#pragma unroll
  for (int a = 0; a < 2; ++a)
#pragma unroll
    for (int b = 0; b < 2; ++b)
#pragma unroll
      for (int r = 0; r < 4; ++r) acc[a][b][r] = make_float4(0.f, 0.f, 0.f, 0.f);

#define FMA4(dst, s, b4) dst.x += (s) * b4.x; dst.y += (s) * b4.y; dst.z += (s) * b4.z; dst.w += (s) * b4.w;
#define GEMM_CHUNK() \
  _Pragma("unroll 8") \
  for (int tk = 0; tk < 32; ++tk) { \
    float4 aL = *(const float4*)&LtT[tk * 132 + (ty << 2)]; \
    float4 aH = *(const float4*)&LtT[tk * 132 + (ty << 2) + 64]; \
    float4 bL = *(const float4*)&Ut[tk * 132 + (tx << 2)]; \
    float4 bH = *(const float4*)&Ut[tk * 132 + (tx << 2) + 64]; \
    FMA4(acc[0][0][0], aL.x, bL) FMA4(acc[0][0][1], aL.y, bL) FMA4(acc[0][0][2], aL.z, bL) FMA4(acc[0][0][3], aL.w, bL) \
    FMA4(acc[0][1][0], aL.x, bH) FMA4(acc[0][1][1], aL.y, bH) FMA4(acc[0][1][2], aL.z, bH) FMA4(acc[0][1][3], aL.w, bH) \
    FMA4(acc[1][0][0], aH.x, bL) FMA4(acc[1][0][1], aH.y, bL) FMA4(acc[1][0][2], aH.z, bL) FMA4(acc[1][0][3], aH.w, bL) \
    FMA4(acc[1][1][0], aH.x, bH) FMA4(acc[1][1][1], aH.y, bH) FMA4(acc[1][1][2], aH.z, bH) FMA4(acc[1][1][3], aH.w, bH) \
  }

  GEMM_CHUNK()   // chunk A
  __syncthreads();

  // LtT chunk B: L21 cols 32..63
  for (int x = tid; x < 1024; x += 256) {
    int rI = x >> 3, q = (x & 7) << 2;
    float4 v = {0.f, 0.f, 0.f, 0.f};
    if (r0 + rI < mprime) v = *(const float4*)(Mk + (size_t)(j0 + 64 + r0 + rI) * N_ + j0 + 32 + q);
    LtT[(q + 0) * 132 + rI] = v.x;
    LtT[(q + 1) * 132 + rI] = v.y;
    LtT[(q + 2) * 132 + rI] = v.z;
    LtT[(q + 3) * 132 + rI] = v.w;
  }
  // TRSM chunk B: rows 32..63, seeded by u[0..31] kept in registers
  if (tcol) {
    float u2[32];
#pragma unroll
    for (int rr = 32; rr < 64; ++rr) {
      float av = ok ? Mk[(size_t)prU[rr] * N_ + j0 + 64 + c] : 0.f;
#pragma unroll
      for (int tt = 0; tt < 32; ++tt) av -= l11[rr * 68 + tt] * u[tt];
#pragma unroll
      for (int tt = 32; tt < 64; ++tt) { if (tt < rr) av -= l11[rr * 68 + tt] * u2[tt - 32]; }
      u2[rr - 32] = av;
      Ut[(rr - 32) * 132 + tid] = av;
    }
  }
  __syncthreads();

  GEMM_CHUNK()   // chunk B
#undef GEMM_CHUNK
#undef FMA4

  // C tile read-modify-write (rowmap-indirect rows)
  int cc = c0 + (tx << 2);
#pragma unroll
  for (int ri = 0; ri < 2; ++ri)
#pragma unroll
    for (int r = 0; r < 4; ++r) {
      int lr = (ty << 2) + r + (ri << 6);
      int pr = rowL[lr];
      if (pr < 0) continue;
      float* rowp = Mk + (size_t)pr * N_ + j0 + 64;
#pragma unroll
      for (int ci = 0; ci < 2; ++ci) {
        int lc = cc + (ci << 6);
        if (lc < mprime) {
          float4* p = (float4*)(rowp + lc);
          float4 cur = *p;
          cur.x -= acc[ri][ci][r].x;
          cur.y -= acc[ri][ci][r].y;
          cur.z -= acc[ri][ci][r].z;
          cur.w -= acc[ri][ci][r].w;
          *p = cur;
        }
      }
    }
}

// ---------------- final: cross term, lle, softmax ----------------
__global__ __launch_bounds__(256) void finalk(const float* __restrict__ X, const float* __restrict__ rbuf,
                                              const float* __restrict__ cterm, const float* __restrict__ logdet,
                                              const float* __restrict__ Qp, float* __restrict__ out) {
  int b = blockIdx.x;
  __shared__ float Xs[1024];
  __shared__ float lleS[32];
  int tid = threadIdx.x, wave = tid >> 6, lane = tid & 63;
  for (int i = tid; i < 1024; i += 256) Xs[i] = X[(size_t)b * 1024 + i];
  __syncthreads();
#pragma unroll
  for (int kk = 0; kk < 8; ++kk) {
    int k = wave + (kk << 2);
    const float* rk = rbuf + (size_t)k * 1024;
    float acc = 0.f;
#pragma unroll
    for (int ch = 0; ch < 4; ++ch) {
      int e4 = (ch * 64 + lane) << 2;
      const float4 rv = *(const float4*)(rk + e4);
      const float4 xv = *(const float4*)&Xs[e4];
      acc += rv.x * xv.x + rv.y * xv.y + rv.z * xv.z + rv.w * xv.w;
    }
    for (int off = 32; off; off >>= 1) acc += __shfl_xor(acc, off);
    if (lane == 0) {
      float Qv = 0.f;
#pragma unroll
      for (int g = 0; g < 4; ++g) Qv += Qp[((size_t)(g * B_ + b) << 5) + k];
      float P1 = Qv - 2.f * acc + cterm[k];
      lleS[k] = -0.5f * P1 + logdet[k];
    }
  }
  __syncthreads();
  if (wave == 0) {
    float v = lleS[lane & 31];
    float mx = v;
    for (int off = 16; off; off >>= 1) mx = fmaxf(mx, __shfl_xor(mx, off));
    float e = expf(v - mx);
    float s = e;
    for (int off = 16; off; off >>= 1) s += __shfl_xor(s, off);
    if (lane < 32) out[b * 32 + lane] = e / s;
  }
}

extern "C" void kernel_launch(void* const* d_in, const int* in_sizes, int n_in,
                              void* d_out, int out_size, void* d_ws, size_t ws_size,
                              hipStream_t stream) {
  const float* X  = (const float*)d_in[0];
  const float* mu = (const float*)d_in[1];
  const float* A  = (const float*)d_in[2];
  float* out = (float*)d_out;
  float* ws  = (float*)d_ws;

  if (ws_size < 134742272ull) {
    hipMemsetAsync(d_out, 0, (size_t)out_size * sizeof(float), stream);
    return;
  }

  float* M      = ws;                        // 33554432 floats (128 MB)
  int*   rowmap = (int*)(ws + 33554432);     // 32768 ints
  float* logdet = ws + 33587200;             // 32
  float* rbuf   = ws + 33587232;             // 32768
  float* cterm  = ws + 33620000;             // 32
  float* Qp     = ws + 33620032;             // 65536

  initk<<<dim3(128), dim3(256), 0, stream>>>(rowmap, logdet);
  buildM<<<dim3(16, 16, 32), dim3(256), 0, stream>>>(A, M);
  prepk<<<dim3(32), dim3(256), 0, stream>>>(A, mu, rbuf, cterm);
  qkern<<<dim3(4, 128), dim3(256), 0, stream>>>(X, A, Qp);

  for (int s = 0; s < 16; ++s) {
    int j0 = s * 64;
    int m = N_ - j0;                         // always a multiple of 64, <= 1024
    panelk<<<dim3(32), dim3(m), 0, stream>>>(M, rowmap, logdet, j0);
    int mprime = m - 64;
    if (mprime > 0) {
      int mt = (mprime + 127) >> 7;
      updatek<<<dim3(mt, mt, 32), dim3(256), 0, stream>>>(M, rowmap, j0);
    }
  }

  finalk<<<dim3(512), dim3(256), 0, stream>>>(X, rbuf, cterm, logdet, Qp, out);
}

// Round 5
// 2624.794 us; speedup vs baseline: 4.3265x; 4.3265x over previous
//
#include <hip/hip_runtime.h>
#include <math.h>

static constexpr int B_ = 512;
static constexpr int T_ = 16;
static constexpr int S_ = 64;
static constexpr int K_ = 32;
static constexpr int N_ = 1024;   // T_*S_

// ---------------- init: rowmap identity + logdet zero ----------------
__global__ void initk(int* __restrict__ rowmap, float* __restrict__ logdet) {
  int idx = blockIdx.x * 256 + threadIdx.x;
  if (idx < K_ * N_) rowmap[idx] = idx & (N_ - 1);
  if (idx < K_) logdet[idx] = 0.f;
}

// ---------------- build block-Toeplitz M[k][row][col], LDS-transpose version ----
// block (i=by rows, j=bx cols): M_block = A[i-j]^T if i>=j else A[j-i]
__global__ __launch_bounds__(256) void buildM(const float* __restrict__ A, float* __restrict__ M) {
  int k = blockIdx.z, i = blockIdx.y, j = blockIdx.x;
  int d = i - j;
  int ad = d >= 0 ? d : -d;
  const float* Ad = A + ((size_t)(ad * K_ + k) << 12);
  float* out = M + ((size_t)k << 20) + (size_t)(i * 64) * N_ + j * 64;
  int tid = threadIdx.x;
  if (d < 0) {
    for (int x = tid; x < 1024; x += 256) {
      int a = x >> 4, b4 = (x & 15) << 2;
      *(float4*)(out + (size_t)a * N_ + b4) = *(const float4*)(Ad + a * 64 + b4);
    }
  } else {
    __shared__ float ts[64][65];
    for (int x = tid; x < 1024; x += 256) {
      int r = x >> 4, c4 = (x & 15) << 2;
      float4 v = *(const float4*)(Ad + r * 64 + c4);
      ts[c4 + 0][r] = v.x; ts[c4 + 1][r] = v.y; ts[c4 + 2][r] = v.z; ts[c4 + 3][r] = v.w;
    }
    __syncthreads();
    for (int x = tid; x < 1024; x += 256) {
      int a = x >> 4, b4 = (x & 15) << 2;
      float4 v;
      v.x = ts[a][b4 + 0]; v.y = ts[a][b4 + 1]; v.z = ts[a][b4 + 2]; v.w = ts[a][b4 + 3];
      *(float4*)(out + (size_t)a * N_ + b4) = v;
    }
  }
}

// ---------------- prep: r[k][j][s] and cterm[k] ----------------
__global__ __launch_bounds__(256) void prepk(const float* __restrict__ A, const float* __restrict__ mu,
                                             float* __restrict__ rbuf, float* __restrict__ cterm) {
  int k = blockIdx.x;
  __shared__ float smu[64];
  __shared__ float sp[1024], sq[1024];
  int tid = threadIdx.x;
  if (tid < 64) smu[tid] = mu[k * 64 + tid];
  __syncthreads();
  for (int idx = tid; idx < 1024; idx += 256) {
    int d = idx >> 6, s = idx & 63;
    const float* Ad = A + ((size_t)(d * K_ + k) << 12);
    float ap = 0.f, aq = 0.f;
    for (int s2 = 0; s2 < 64; ++s2) {
      ap += Ad[s * 64 + s2] * smu[s2];
      aq += Ad[s2 * 64 + s] * smu[s2];
    }
    sp[idx] = ap; sq[idx] = aq;
  }
  __syncthreads();
  for (int idx = tid; idx < 1024; idx += 256) {
    int j = idx >> 6, s = idx & 63;
    float acc = 0.5f * (sp[s] + sq[s]);
    for (int d = 1; d < 16; ++d) {
      if (d <= 15 - j) acc += sp[d * 64 + s];
      if (d <= j)      acc += sq[d * 64 + s];
    }
    rbuf[k * 1024 + idx] = acc;
  }
  if (tid < 64) {
    float a = 16.f * sp[tid];
    for (int d = 1; d < 16; ++d) a += 2.f * (float)(16 - d) * sp[d * 64 + tid];
    a *= smu[tid];
    for (int off = 32; off; off >>= 1) a += __shfl_xor(a, off);
    if (tid == 0) cterm[k] = a;
  }
}

// ---------------- Q kernel: Qp[g][b][k] partial quadratic forms ----------------
__global__ __launch_bounds__(256) void qkern(const float* __restrict__ X, const float* __restrict__ A,
                                             float* __restrict__ Qp) {
  int g = blockIdx.x;        // d in {g, g+4, g+8, g+12}
  int btile = blockIdx.y;    // 4 batches each
  __shared__ float Xs[4][1024];
  __shared__ float Cs[4][4096];
  int tid = threadIdx.x;
  int wave = tid >> 6, lane = tid & 63;
  for (int t = tid; t < 4096; t += 256) {
    int bb = t >> 10, e = t & 1023;
    Xs[bb][e] = X[(size_t)(btile * 4 + bb) * 1024 + e];
  }
  float regQ[4][8];
#pragma unroll
  for (int bb = 0; bb < 4; ++bb)
#pragma unroll
    for (int kk = 0; kk < 8; ++kk) regQ[bb][kk] = 0.f;

  int a0 = (tid >> 4) << 2;
  int v0 = (tid & 15) << 2;
  for (int dd = 0; dd < 4; ++dd) {
    int d = g + (dd << 2);
    __syncthreads();
    for (int bb = 0; bb < 4; ++bb) {
      float4 r0 = {0,0,0,0}, r1 = {0,0,0,0}, r2 = {0,0,0,0}, r3 = {0,0,0,0};
      for (int j = 0; j + d < 16; ++j) {
        const float4 xa = *(const float4*)&Xs[bb][j * 64 + a0];
        const float4 xv = *(const float4*)&Xs[bb][(j + d) * 64 + v0];
        r0.x += xa.x * xv.x; r0.y += xa.x * xv.y; r0.z += xa.x * xv.z; r0.w += xa.x * xv.w;
        r1.x += xa.y * xv.x; r1.y += xa.y * xv.y; r1.z += xa.y * xv.z; r1.w += xa.y * xv.w;
        r2.x += xa.z * xv.x; r2.y += xa.z * xv.y; r2.z += xa.z * xv.z; r2.w += xa.z * xv.w;
        r3.x += xa.w * xv.x; r3.y += xa.w * xv.y; r3.z += xa.w * xv.z; r3.w += xa.w * xv.w;
      }
      *(float4*)&Cs[bb][(a0 + 0) * 64 + v0] = r0;
      *(float4*)&Cs[bb][(a0 + 1) * 64 + v0] = r1;
      *(float4*)&Cs[bb][(a0 + 2) * 64 + v0] = r2;
      *(float4*)&Cs[bb][(a0 + 3) * 64 + v0] = r3;
    }
    __syncthreads();
    float w = (d == 0) ? 1.f : 2.f;
    for (int ch = 0; ch < 16; ++ch) {
      int e4 = (ch * 64 + lane) << 2;
      float4 cv[4];
#pragma unroll
      for (int bb = 0; bb < 4; ++bb) {
        float4 t4 = *(const float4*)&Cs[bb][e4];
        cv[bb].x = w * t4.x; cv[bb].y = w * t4.y; cv[bb].z = w * t4.z; cv[bb].w = w * t4.w;
      }
#pragma unroll
      for (int kk = 0; kk < 8; ++kk) {
        int k = wave + (kk << 2);
        const float4 av = *(const float4*)(A + (((size_t)(d * K_ + k)) << 12) + e4);
#pragma unroll
        for (int bb = 0; bb < 4; ++bb)
          regQ[bb][kk] += av.x * cv[bb].x + av.y * cv[bb].y + av.z * cv[bb].z + av.w * cv[bb].w;
      }
    }
  }
#pragma unroll
  for (int bb = 0; bb < 4; ++bb)
#pragma unroll
    for (int kk = 0; kk < 8; ++kk) {
      float v = regQ[bb][kk];
      for (int off = 32; off; off >>= 1) v += __shfl_xor(v, off);
      regQ[bb][kk] = v;
    }
  if (lane == 0) {
    int b = btile * 4;
#pragma unroll
    for (int bb = 0; bb < 4; ++bb)
#pragma unroll
      for (int kk = 0; kk < 8; ++kk)
        Qp[((size_t)(g * B_ + b + bb) << 5) + (wave + (kk << 2))] = regQ[bb][kk];
  }
}

// ---------------- LU panel (nb=32) v5: register rows + fused TRSM epilogue ----------------
// Factor phase identical to proven v3. Epilogue: threads solve U12 = L11^{-1} A12
// once (one column per thread, coalesced row reads) into Uws[k][32][1024].
__global__ __launch_bounds__(1024) void panelk(float* __restrict__ M, int* __restrict__ rowmap,
                                               float* __restrict__ logdet, float* __restrict__ Uws,
                                               int j0) {
  int k = blockIdx.x;
  float* Mk = M + ((size_t)k << 20);
  int* rmk = rowmap + (k << 10);
  int m = N_ - j0;
  int t = threadIdx.x;
  int bdim = blockDim.x;
  int lane = t & 63, wid = t >> 6;
  int nw = (bdim + 63) >> 6;

  __shared__ float bufP[32];
  __shared__ float bufJ[32];
  __shared__ int origP, origJ;
  __shared__ float candv[16];
  __shared__ int candi[16];
  __shared__ int spiv;
  __shared__ float l11s[32 * 33];
  __shared__ int smapU[32];

  float r[32];
  int myorig = -1;
  float mydiag = 1.f;
  bool act = (t < m);
  if (act) {
    myorig = rmk[j0 + t];
    const float* src = Mk + (size_t)myorig * N_ + j0;
#pragma unroll
    for (int c4 = 0; c4 < 8; ++c4) *(float4*)&r[c4 * 4] = *(const float4*)(src + c4 * 4);
  }

#pragma unroll
  for (int jj = 0; jj < 32; ++jj) {
    // ---- phase 1: per-wave argmax of |r[jj]| over t in [jj, m) ----
    float bv = (act && t >= jj) ? fabsf(r[jj]) : -1.f;
    int bi = t;
#pragma unroll
    for (int off = 32; off; off >>= 1) {
      float ov = __shfl_xor(bv, off);
      int oi = __shfl_xor(bi, off);
      if (ov > bv) { bv = ov; bi = oi; }
    }
    if (lane == 0) { candv[wid] = bv; candi[wid] = bi; }
    __syncthreads();
    // ---- phase 2: wave 0 reduces the <=16 wave candidates ----
    if (t < 64) {
      float cv = (lane < nw) ? candv[lane] : -1.f;
      int ci = (lane < nw) ? candi[lane] : 0;
#pragma unroll
      for (int off = 8; off; off >>= 1) {
        float ov = __shfl_down(cv, off, 16);
        int oi = __shfl_down(ci, off, 16);
        if (ov > cv) { cv = ov; ci = oi; }
      }
      if (lane == 0) spiv = ci;
    }
    __syncthreads();
    int p = spiv;
    // ---- phase 3: stage pivot row (and displaced row jj if swapping) ----
    if (t == p) {
#pragma unroll
      for (int c4 = 0; c4 < 8; ++c4) *(float4*)&bufP[c4 * 4] = *(const float4*)&r[c4 * 4];
      origP = myorig;
    }
    if (p != jj && t == jj) {
#pragma unroll
      for (int c4 = 0; c4 < 8; ++c4) *(float4*)&bufJ[c4 * 4] = *(const float4*)&r[c4 * 4];
      origJ = myorig;
    }
    __syncthreads();
    // ---- phase 4: adopt swaps; broadcast pivot row; rank-1 update ----
    float pr[32];
#pragma unroll
    for (int c4 = 0; c4 < 8; ++c4) *(float4*)&pr[c4 * 4] = *(const float4*)&bufP[c4 * 4];
    if (p != jj) {
      if (t == jj) {
#pragma unroll
        for (int c = 0; c < 32; ++c) r[c] = pr[c];
        myorig = origP;
      } else if (t == p) {
#pragma unroll
        for (int c4 = 0; c4 < 8; ++c4) *(float4*)&r[c4 * 4] = *(const float4*)&bufJ[c4 * 4];
        myorig = origJ;
      }
    }
    float pv = pr[jj];
    if (t == jj) mydiag = pv;
    float sinv = 1.0f / pv;
    if (act && t > jj) {
      float mult = r[jj] * sinv;
      r[jj] = mult;
#pragma unroll
      for (int c = jj + 1; c < 32; ++c) r[c] -= mult * pr[c];
    }
    // next step's phase-1/2 barriers fence bufP/bufJ/spiv reuse
  }

  // ---- logdet from saved diagonals ----
  if (t < 32) {
    float lv = logf(fabsf(mydiag));
#pragma unroll
    for (int off = 16; off; off >>= 1) lv += __shfl_down(lv, off, 32);
    if (t == 0) logdet[k] += lv;
  }
  // ---- stage L11\U11 + pivoted-row origins for the TRSM epilogue ----
  if (t < 32) {
#pragma unroll
    for (int c = 0; c < 32; ++c) l11s[t * 33 + c] = r[c];
    smapU[t] = myorig;
  }
  // ---- export L/U panel (pivoted order, dense) + rowmap writeback ----
  if (act) {
    float* dst = Mk + (size_t)(j0 + t) * N_ + j0;
#pragma unroll
    for (int c4 = 0; c4 < 8; ++c4) *(float4*)(dst + c4 * 4) = *(const float4*)&r[c4 * 4];
    rmk[j0 + t] = myorig;
  }
  __syncthreads();

  // ---- fused TRSM: U12 = L11^{-1} A12, one column per thread, solved ONCE ----
  int mprime = m - 32;
  if (t < mprime) {
    int col = j0 + 32 + t;
    float* Uk = Uws + ((size_t)k << 15);
    float u[32];
#pragma unroll
    for (int rr = 0; rr < 32; ++rr) {
      float av = Mk[(size_t)smapU[rr] * N_ + col];
#pragma unroll
      for (int tt = 0; tt < 32; ++tt) { if (tt < rr) av -= l11s[rr * 33 + tt] * u[tt]; }
      u[rr] = av;
      Uk[(rr << 10) + col] = av;
    }
  }
}

// ---------------- trailing GEMM update, 128x128 C tile, C-early-load ----------------
__global__ __launch_bounds__(256) void updatek(float* __restrict__ M, const int* __restrict__ rowmap,
                                               const float* __restrict__ Uws, int j0) {
  int k = blockIdx.z;
  int mprime = N_ - j0 - 32;
  int r0 = blockIdx.y << 7;
  int c0 = blockIdx.x << 7;
  float* Mk = M + ((size_t)k << 20);
  const int* rmk = rowmap + (k << 10);
  __shared__ float LtT[32 * 132];
  __shared__ float Ut[32 * 132];
  __shared__ int rowL[128];
  int tid = threadIdx.x;

  if (tid < 128) rowL[tid] = (r0 + tid < mprime) ? rmk[j0 + 32 + r0 + tid] : -1;
  // stage L21^T from the dense panel export
  for (int x = tid; x < 1024; x += 256) {
    int rI = x >> 3, q = (x & 7) << 2;
    float4 v = {0.f, 0.f, 0.f, 0.f};
    if (r0 + rI < mprime) v = *(const float4*)(Mk + (size_t)(j0 + 32 + r0 + rI) * N_ + j0 + q);
    LtT[(q + 0) * 132 + rI] = v.x;
    LtT[(q + 1) * 132 + rI] = v.y;
    LtT[(q + 2) * 132 + rI] = v.z;
    LtT[(q + 3) * 132 + rI] = v.w;
  }
  // stage U12 tile from Uws (coalesced, already solved)
  {
    const float* Uk = Uws + ((size_t)k << 15) + j0 + 32 + c0;
    for (int x = tid; x < 1024; x += 256) {
      int rr = x >> 5, c4 = (x & 31) << 2;
      float4 v = {0.f, 0.f, 0.f, 0.f};
      if (c0 + c4 < mprime) v = *(const float4*)(Uk + (rr << 10) + c4);
      *(float4*)&Ut[rr * 132 + c4] = v;
    }
  }
  __syncthreads();

  int tx = tid & 15, ty = tid >> 4;
  int cc = c0 + (tx << 2);

  // ---- C tile early load (hides RMW read latency under the GEMM) ----
  float4 cur[2][2][4];
#pragma unroll
  for (int ri = 0; ri < 2; ++ri)
#pragma unroll
    for (int r = 0; r < 4; ++r) {
      int lr = (ty << 2) + r + (ri << 6);
      int pr = rowL[lr];
#pragma unroll
      for (int ci = 0; ci < 2; ++ci) {
        int lc = cc + (ci << 6);
        if (pr >= 0 && lc < mprime)
          cur[ri][ci][r] = *(const float4*)(Mk + (size_t)pr * N_ + j0 + 32 + lc);
        else
          cur[ri][ci][r] = make_float4(0.f, 0.f, 0.f, 0.f);
      }
    }

  // ---- GEMM: accumulate -= L21*U12 directly into the loaded C registers ----
#define FMS4(dst, s, b4) dst.x -= (s) * b4.x; dst.y -= (s) * b4.y; dst.z -= (s) * b4.z; dst.w -= (s) * b4.w;
#pragma unroll 8
  for (int tk = 0; tk < 32; ++tk) {
    float4 aL = *(const float4*)&LtT[tk * 132 + (ty << 2)];
    float4 aH = *(const float4*)&LtT[tk * 132 + (ty << 2) + 64];
    float4 bL = *(const float4*)&Ut[tk * 132 + (tx << 2)];
    float4 bH = *(const float4*)&Ut[tk * 132 + (tx << 2) + 64];
    FMS4(cur[0][0][0], aL.x, bL) FMS4(cur[0][0][1], aL.y, bL) FMS4(cur[0][0][2], aL.z, bL) FMS4(cur[0][0][3], aL.w, bL)
    FMS4(cur[0][1][0], aL.x, bH) FMS4(cur[0][1][1], aL.y, bH) FMS4(cur[0][1][2], aL.z, bH) FMS4(cur[0][1][3], aL.w, bH)
    FMS4(cur[1][0][0], aH.x, bL) FMS4(cur[1][0][1], aH.y, bL) FMS4(cur[1][0][2], aH.z, bL) FMS4(cur[1][0][3], aH.w, bL)
    FMS4(cur[1][1][0], aH.x, bH) FMS4(cur[1][1][1], aH.y, bH) FMS4(cur[1][1][2], aH.z, bH) FMS4(cur[1][1][3], aH.w, bH)
  }
#undef FMS4

  // ---- store back ----
#pragma unroll
  for (int ri = 0; ri < 2; ++ri)
#pragma unroll
    for (int r = 0; r < 4; ++r) {
      int lr = (ty << 2) + r + (ri << 6);
      int pr = rowL[lr];
      if (pr < 0) continue;
      float* rowp = Mk + (size_t)pr * N_ + j0 + 32;
#pragma unroll
      for (int ci = 0; ci < 2; ++ci) {
        int lc = cc + (ci << 6);
        if (lc < mprime) *(float4*)(rowp + lc) = cur[ri][ci][r];
      }
    }
}

// ---------------- final: cross term, lle, softmax ----------------
__global__ __launch_bounds__(256) void finalk(const float* __restrict__ X, const float* __restrict__ rbuf,
                                              const float* __restrict__ cterm, const float* __restrict__ logdet,
                                              const float* __restrict__ Qp, float* __restrict__ out) {
  int b = blockIdx.x;
  __shared__ float Xs[1024];
  __shared__ float lleS[32];
  int tid = threadIdx.x, wave = tid >> 6, lane = tid & 63;
  for (int i = tid; i < 1024; i += 256) Xs[i] = X[(size_t)b * 1024 + i];
  __syncthreads();
#pragma unroll
  for (int kk = 0; kk < 8; ++kk) {
    int k = wave + (kk << 2);
    const float* rk = rbuf + (size_t)k * 1024;
    float acc = 0.f;
#pragma unroll
    for (int ch = 0; ch < 4; ++ch) {
      int e4 = (ch * 64 + lane) << 2;
      const float4 rv = *(const float4*)(rk + e4);
      const float4 xv = *(const float4*)&Xs[e4];
      acc += rv.x * xv.x + rv.y * xv.y + rv.z * xv.z + rv.w * xv.w;
    }
    for (int off = 32; off; off >>= 1) acc += __shfl_xor(acc, off);
    if (lane == 0) {
      float Qv = 0.f;
#pragma unroll
      for (int g = 0; g < 4; ++g) Qv += Qp[((size_t)(g * B_ + b) << 5) + k];
      float P1 = Qv - 2.f * acc + cterm[k];
      lleS[k] = -0.5f * P1 + logdet[k];
    }
  }
  __syncthreads();
  if (wave == 0) {
    float v = lleS[lane & 31];
    float mx = v;
    for (int off = 16; off; off >>= 1) mx = fmaxf(mx, __shfl_xor(mx, off));
    float e = expf(v - mx);
    float s = e;
    for (int off = 16; off; off >>= 1) s += __shfl_xor(s, off);
    if (lane < 32) out[b * 32 + lane] = e / s;
  }
}

extern "C" void kernel_launch(void* const* d_in, const int* in_sizes, int n_in,
                              void* d_out, int out_size, void* d_ws, size_t ws_size,
                              hipStream_t stream) {
  const float* X  = (const float*)d_in[0];
  const float* mu = (const float*)d_in[1];
  const float* A  = (const float*)d_in[2];
  float* out = (float*)d_out;
  float* ws  = (float*)d_ws;

  if (ws_size < 138936576ull) {   // 128 MB M + maps + 4 MB U stripe
    hipMemsetAsync(d_out, 0, (size_t)out_size * sizeof(float), stream);
    return;
  }

  float* M      = ws;                        // 33554432 floats (128 MB)
  int*   rowmap = (int*)(ws + 33554432);     // 32768 ints
  float* logdet = ws + 33587200;             // 32
  float* rbuf   = ws + 33587232;             // 32768
  float* cterm  = ws + 33620000;             // 32
  float* Qp     = ws + 33620032;             // 65536
  float* Uws    = ws + 33685568;             // 32*32*1024 = 1048576 floats (4 MB)

  initk<<<dim3(128), dim3(256), 0, stream>>>(rowmap, logdet);
  buildM<<<dim3(16, 16, 32), dim3(256), 0, stream>>>(A, M);
  prepk<<<dim3(32), dim3(256), 0, stream>>>(A, mu, rbuf, cterm);
  qkern<<<dim3(4, 128), dim3(256), 0, stream>>>(X, A, Qp);

  for (int s = 0; s < 32; ++s) {
    int j0 = s * 32;
    int m = N_ - j0;
    int bt = ((m + 63) >> 6) << 6;           // threads = rows, rounded to wave
    panelk<<<dim3(32), dim3(bt), 0, stream>>>(M, rowmap, logdet, Uws, j0);
    int mprime = m - 32;
    if (mprime > 0) {
      int mt = (mprime + 127) >> 7;
      updatek<<<dim3(mt, mt, 32), dim3(256), 0, stream>>>(M, rowmap, Uws, j0);
    }
  }

  finalk<<<dim3(512), dim3(256), 0, stream>>>(X, rbuf, cterm, logdet, Qp, out);
}